// Round 11
// baseline (191.854 us; speedup 1.0000x reference)
//
#include <hip/hip_runtime.h>
#include <hip/hip_bf16.h>
#include <stdint.h>
#include <math.h>

// NT-Xent contrastive loss, N=4096, D=1024, 2N=8192 rows.
// knorm (normalize + bf16 + zero side-buffers + queue ctr) ->
// ksim (upper-triangle 128^2 bf16 MFMA GEMM, BK=64, persistent work-queue,
//       row+col sums per tile) -> kfinal (exact positives + lse + mean).

#define NROWS 8192
#define HALFN 4096
#define DIM   1024
#define NTILES 2080     // 64*65/2 upper-triangle 128^2 tiles
#define INV_T 14.285714285714286f   // 1/0.07; fixed LSE shift C (sim <= 1/T)

typedef __bf16 bf16x8 __attribute__((ext_vector_type(8)));
typedef float  f32x4  __attribute__((ext_vector_type(4)));

__device__ __forceinline__ unsigned short f2bf(float x) {
  union { float f; uint32_t u; } c; c.f = x;
  uint32_t u = c.u;
  return (unsigned short)((u + 0x7FFFu + ((u >> 16) & 1u)) >> 16);
}

__device__ __forceinline__ void gload16(const void* g, void* lds) {
  __builtin_amdgcn_global_load_lds(
      (const __attribute__((address_space(1))) unsigned int*)g,
      (__attribute__((address_space(3))) unsigned int*)lds,
      16, 0, 0);
}

// ---------------- kernel A: row L2-normalize + bf16 convert ----------------
__global__ __launch_bounds__(256) void knorm(const float* __restrict__ zi,
                                             const float* __restrict__ zj,
                                             __bf16* __restrict__ znb,
                                             float* __restrict__ rnorm,
                                             float* __restrict__ rowsum,
                                             float* __restrict__ out,
                                             unsigned* __restrict__ ctr) {
  int r = blockIdx.x;
  const float* z = (r < HALFN) ? (zi + (size_t)r * DIM)
                               : (zj + (size_t)(r - HALFN) * DIM);
  int t = threadIdx.x;
  float4 v = ((const float4*)z)[t];
  float ss = v.x*v.x + v.y*v.y + v.z*v.z + v.w*v.w;
  for (int m = 32; m; m >>= 1) ss += __shfl_xor(ss, m);
  __shared__ float wss[4];
  if ((t & 63) == 0) wss[t >> 6] = ss;
  __syncthreads();
  float nrm = sqrtf(wss[0] + wss[1] + wss[2] + wss[3]);
  nrm = fmaxf(nrm, 1e-8f);
  float rn = 1.0f / nrm;
  if (t == 0) {
    rnorm[r] = rn;
    rowsum[r] = 0.f;
    if (r == 0) { out[0] = 0.f; ctr[0] = 0u; }
  }
  ushort4 o;
  o.x = f2bf(v.x * rn); o.y = f2bf(v.y * rn);
  o.z = f2bf(v.z * rn); o.w = f2bf(v.w * rn);
  ((ushort4*)znb)[(size_t)r * (DIM / 4) + t] = o;
}

// ---------------- kernel C: persistent upper-triangle 128^2 sim GEMM -------
// BK=64, 4 waves 2x2 (each 64x64 out), LDS 32KB single-buffered.
// Row stride 128B -> bank cycle drops row: swizzle chunk c ^= (row&7)
// (16 frag-lanes -> 8 chunks = 2-way, free).  768 persistent blocks pop
// tiles from atomic ctr (tail ~1 tile instead of ~1 block).
__global__ __launch_bounds__(256, 3) void ksim(const __bf16* __restrict__ znb,
                                               float* __restrict__ rowsum,
                                               unsigned* __restrict__ ctr) {
  __shared__ __align__(16) __bf16 As[128 * 64];   // 16 KB
  __shared__ __align__(16) __bf16 Bs[128 * 64];   // 16 KB
  __shared__ unsigned s_u;

  int t = threadIdx.x;
  int w = t >> 6, l = t & 63;
  int wr = w >> 1, wc = w & 1;     // 2x2 wave grid, each wave 64x64
  int lr = l & 15, lg = l >> 4;

  int srow = l >> 3;                       // staging: row offset in 8-row group
  int sck  = (l & 7) ^ srow;               // pre-swizzled source chunk (0..7)
  int rsw  = lr & 7;                       // read-side row swizzle term

  const float s2 = INV_T * 1.442695040888963f;

  for (;;) {
    if (t == 0) s_u = atomicAdd(ctr, 1u);
    __syncthreads();                       // broadcast pop + LDS-protect
    unsigned u = s_u;
    if (u >= NTILES) return;

    // invert s(rb) = rb*(129-rb)/2 <= u (fp32 hint + exact integer fixup)
    int rbI = (int)(0.5f * (129.0f - sqrtf(16641.0f - 8.0f * (float)u)));
    while ((rbI + 1) * (129 - (rbI + 1)) / 2 <= (int)u) ++rbI;
    while (rbI * (129 - rbI) / 2 > (int)u) --rbI;
    int cbI = rbI + ((int)u - rbI * (129 - rbI) / 2);

    const __bf16* Aor = znb + (size_t)rbI * 128 * DIM;
    const __bf16* Bor = znb + (size_t)cbI * 128 * DIM;

    f32x4 acc[4][4] = {};

    for (int kt = 0; kt < 16; ++kt) {
      int k0 = kt * 64;
      // stage 32KB: wave w covers rows w*32..w*32+31 in 4 gloads (8 rows ea)
#pragma unroll
      for (int j = 0; j < 4; ++j) {
        int rowu = w * 32 + j * 8;         // wave-uniform row base
        gload16(Aor + (size_t)(rowu + srow) * DIM + k0 + sck * 8,
                (char*)As + rowu * 128);
        gload16(Bor + (size_t)(rowu + srow) * DIM + k0 + sck * 8,
                (char*)Bs + rowu * 128);
      }
      __syncthreads();                     // vmcnt drain: tile resident
#pragma unroll
      for (int ks = 0; ks < 2; ++ks) {     // two K=32 subtiles, no barrier
        bf16x8 af[4], bg[4];
#pragma unroll
        for (int m = 0; m < 4; ++m) {
          int rowa = wr * 64 + m * 16 + lr;
          af[m] = *(const bf16x8*)((const char*)As + rowa * 128 +
                                   (((ks * 4 + lg) ^ rsw) * 16));
          int rowb = wc * 64 + m * 16 + lr;
          bg[m] = *(const bf16x8*)((const char*)Bs + rowb * 128 +
                                   (((ks * 4 + lg) ^ rsw) * 16));
        }
#pragma unroll
        for (int m = 0; m < 4; ++m)
#pragma unroll
          for (int n = 0; n < 4; ++n)
            acc[m][n] = __builtin_amdgcn_mfma_f32_16x16x32_bf16(af[m], bg[n], acc[m][n], 0, 0, 0);
      }
      __syncthreads();                     // reads done before next stage
    }

    // epilogue: e = exp2((dot-1)*s2); diag masked; row sums + col sums
    int growb = rbI * 128 + wr * 64;
    int gcolb = cbI * 128 + wc * 64;
    float csn[4] = {0.f, 0.f, 0.f, 0.f};
#pragma unroll
    for (int m = 0; m < 4; ++m) {
      float s[4] = {0.f, 0.f, 0.f, 0.f};
#pragma unroll
      for (int n = 0; n < 4; ++n) {
        int gcol = gcolb + n * 16 + lr;                // C/D: col = lane&15
#pragma unroll
        for (int j = 0; j < 4; ++j) {
          int grow = growb + m * 16 + lg * 4 + j;      // row = (lane>>4)*4+j
          float e = exp2f(fmaf(acc[m][n][j], s2, -s2));
          if (grow == gcol) e = 0.f;                   // diag (rb==cb only)
          s[j] += e;
          csn[n] += e;
        }
      }
#pragma unroll
      for (int j = 0; j < 4; ++j) {
        float v = s[j];
        v += __shfl_xor(v, 1);
        v += __shfl_xor(v, 2);
        v += __shfl_xor(v, 4);
        v += __shfl_xor(v, 8);
        if (lr == 0)
          atomicAdd(rowsum + growb + m * 16 + lg * 4 + j, v);
      }
    }
    if (rbI != cbI) {                      // transpose contribution
#pragma unroll
      for (int n = 0; n < 4; ++n) {
        float v = csn[n];
        v += __shfl_xor(v, 16);
        v += __shfl_xor(v, 32);
        if (lg == 0)
          atomicAdd(rowsum + gcolb + n * 16 + lr, v);
      }
    }
  }
}

// ---------------- kernel D: positives + lse + mean, low atomic contention --
__global__ __launch_bounds__(256) void kfinal(const float* __restrict__ zi,
                                              const float* __restrict__ zj,
                                              const float* __restrict__ rnorm,
                                              const float* __restrict__ rowsum,
                                              float* __restrict__ out) {
  int t = threadIdx.x;
  int w = t >> 6, l = t & 63;
  float accum = 0.f;
#pragma unroll
  for (int sw = 0; sw < 4; ++sw) {
    int r = blockIdx.x * 4 + w + sw * 1024;    // pair index 0..HALFN-1
    const float* zr = zi + (size_t)r * DIM;
    const float* zp = zj + (size_t)r * DIM;
    float dot = 0.f;
#pragma unroll
    for (int j = 0; j < 4; ++j) {
      float4 a = ((const float4*)zr)[j * 64 + l];
      float4 b = ((const float4*)zp)[j * 64 + l];
      dot += a.x*b.x + a.y*b.y + a.z*b.z + a.w*b.w;
    }
    for (int m = 32; m; m >>= 1) dot += __shfl_xor(dot, m);
    if (l == 0) {
      float lse_r = logf(rowsum[r]) + INV_T;
      float lse_p = logf(rowsum[r + HALFN]) + INV_T;
      float pos = dot * rnorm[r] * rnorm[r + HALFN] * INV_T;
      accum += lse_r + lse_p - 2.0f * pos;
    }
  }
  __shared__ float part[4];
  if (l == 0) part[w] = accum;
  __syncthreads();
  if (t == 0)
    atomicAdd(out, (part[0] + part[1] + part[2] + part[3]) * (1.0f / (float)NROWS));
}

// ---------------- launch ----------------
extern "C" void kernel_launch(void* const* d_in, const int* in_sizes, int n_in,
                              void* d_out, int out_size, void* d_ws, size_t ws_size,
                              hipStream_t stream) {
  const float* zi = (const float*)d_in[0];
  const float* zj = (const float*)d_in[1];
  float* out = (float*)d_out;
  char* ws = (char*)d_ws;
  __bf16* znb    = (__bf16*)ws;                                   // 16 MB
  float*  rnorm  = (float*)(ws + (size_t)NROWS * DIM * 2);        // 32 KB
  float*  rowsum = (float*)(ws + (size_t)NROWS * DIM * 2 + NROWS * 4);
  unsigned* ctr  = (unsigned*)(ws + (size_t)NROWS * DIM * 2 + 2 * NROWS * 4);

  knorm<<<NROWS, 256, 0, stream>>>(zi, zj, znb, rnorm, rowsum, out, ctr);
  ksim<<<768, 256, 0, stream>>>(znb, rowsum, ctr);
  kfinal<<<256, 256, 0, stream>>>(zi, zj, rnorm, rowsum, out);
}